// Round 11
// baseline (408.550 us; speedup 1.0000x reference)
//
#include <hip/hip_runtime.h>

// Problem constants (from reference)
#define B_  16
#define T_  2048
#define IN_ 512
#define H_  512
#define M_  (B_ * T_)

// GEMM tiling — R5 schedule (the measured optimum: 212->205us, VGPR 116)
// plus alternating LDS buffers to drop the trailing barrier (64 -> 32
// barriers/tile-loop) with ZERO extra register liveness.
// History: R6 (256,4) bound -> acc spill -> 3048us. R7 2-reg-set ping-pong
// -> VGPR 192 -> 298us. R8 persistent fusion -> occupancy coupling -> 529us.
// R9 mid-compute staging -> vmcnt drain mid-tile -> 230us.
#define BM 128
#define BN 128
#define BK 16
#define LDT (BM + 4)

static __device__ __forceinline__ float4 ld4(const float* p) {
    return *reinterpret_cast<const float4*>(p);
}

// ---------------------------------------------------------------------------
// Kernel 1: h[m][n] = sum_k x[m][k]*W[n][k] + b[n], fp32 VALU.
// k accumulated strictly in order 0..511 with fmaf -> bit-matches np ref
// (absmax 0.0 across R2-R10). DO NOT reorder the k loop.
// Safety of single barrier/tile: barrier-i sits between stores-i and
// compute-i. Any wave entering stores-(i+1) (buffer b^1) has passed
// barrier-i, which means ALL waves finished compute-(i-1) — the only
// readers of buffer b^1. Stores-(i+1) never race live reads.
// ---------------------------------------------------------------------------
__global__ __launch_bounds__(256)
void gemm_xwT(const float* __restrict__ X, const float* __restrict__ W,
              const float* __restrict__ bias, float* __restrict__ Hout) {
    __shared__ float As[2][BK][LDT];
    __shared__ float Bs[2][BK][LDT];

    const int tid = threadIdx.x;
    const int m0  = blockIdx.x * BM;   // 256 m-tiles
    const int n0  = blockIdx.y * BN;   // 4 n-tiles

    const int tx = tid & 15;           // col group
    const int ty = tid >> 4;           // row group

    const int row = tid >> 2;          // 0..63
    const int kph = (tid & 3) * 4;     // 0,4,8,12

    const float* pa0 = X + (size_t)(m0 + row) * IN_ + kph;
    const float* pa1 = pa0 + (size_t)64 * IN_;
    const float* pb0 = W + (size_t)(n0 + row) * IN_ + kph;
    const float* pb1 = pb0 + (size_t)64 * IN_;

    float4 ra0 = ld4(pa0), ra1 = ld4(pa1), rb0 = ld4(pb0), rb1 = ld4(pb1);

    float acc[8][8];
#pragma unroll
    for (int i = 0; i < 8; ++i)
#pragma unroll
        for (int j = 0; j < 8; ++j) acc[i][j] = 0.0f;

    int bsel = 0;
#pragma unroll 1
    for (int k0 = 0; k0 < IN_; k0 += BK) {
        float (*__restrict__ Asb)[LDT] = As[bsel];
        float (*__restrict__ Bsb)[LDT] = Bs[bsel];

        Asb[kph + 0][row]      = ra0.x;  Asb[kph + 1][row]      = ra0.y;
        Asb[kph + 2][row]      = ra0.z;  Asb[kph + 3][row]      = ra0.w;
        Asb[kph + 0][row + 64] = ra1.x;  Asb[kph + 1][row + 64] = ra1.y;
        Asb[kph + 2][row + 64] = ra1.z;  Asb[kph + 3][row + 64] = ra1.w;
        Bsb[kph + 0][row]      = rb0.x;  Bsb[kph + 1][row]      = rb0.y;
        Bsb[kph + 2][row]      = rb0.z;  Bsb[kph + 3][row]      = rb0.w;
        Bsb[kph + 0][row + 64] = rb1.x;  Bsb[kph + 1][row + 64] = rb1.y;
        Bsb[kph + 2][row + 64] = rb1.z;  Bsb[kph + 3][row + 64] = rb1.w;
        __syncthreads();                 // ONE barrier per tile

        // prefetch next k-tile; drains during the 16-k compute below
        if (k0 + BK < IN_) {
            ra0 = ld4(pa0 + k0 + BK);  ra1 = ld4(pa1 + k0 + BK);
            rb0 = ld4(pb0 + k0 + BK);  rb1 = ld4(pb1 + k0 + BK);
        }

#pragma unroll
        for (int k = 0; k < BK; ++k) {
            float4 av0 = ld4(&Asb[k][ty * 4]);
            float4 av1 = ld4(&Asb[k][ty * 4 + 64]);
            float4 bv0 = ld4(&Bsb[k][tx * 4]);
            float4 bv1 = ld4(&Bsb[k][tx * 4 + 64]);
            const float am[8] = {av0.x, av0.y, av0.z, av0.w,
                                 av1.x, av1.y, av1.z, av1.w};
            const float bn8[8] = {bv0.x, bv0.y, bv0.z, bv0.w,
                                  bv1.x, bv1.y, bv1.z, bv1.w};
#pragma unroll
            for (int i = 0; i < 8; ++i)
#pragma unroll
                for (int j = 0; j < 8; ++j)
                    acc[i][j] = fmaf(am[i], bn8[j], acc[i][j]);
        }
        bsel ^= 1;
    }

    // epilogue: + bias (bias is zeros -> exact), coalesced float4 stores
    float4 bb0 = ld4(&bias[n0 + tx * 4]);
    float4 bb1 = ld4(&bias[n0 + tx * 4 + 64]);
#pragma unroll
    for (int i = 0; i < 8; ++i) {
        const int r = m0 + ((i < 4) ? (ty * 4 + i) : (64 + ty * 4 + (i - 4)));
        float4 o0, o1;
        o0.x = acc[i][0] + bb0.x;  o0.y = acc[i][1] + bb0.y;
        o0.z = acc[i][2] + bb0.z;  o0.w = acc[i][3] + bb0.w;
        o1.x = acc[i][4] + bb1.x;  o1.y = acc[i][5] + bb1.y;
        o1.z = acc[i][6] + bb1.z;  o1.w = acc[i][7] + bb1.w;
        *reinterpret_cast<float4*>(&Hout[(size_t)r * H_ + n0 + tx * 4])      = o0;
        *reinterpret_cast<float4*>(&Hout[(size_t)r * H_ + n0 + tx * 4 + 64]) = o1;
    }
}

// ---------------------------------------------------------------------------
// Kernel 2: GIF neuron scan. One thread per (b,h) chain; T=2048 steps.
// Wall = 2048 x dependent-chain period (~193 cyc at R10). R10 showed the
// fma ladder is NOT the pole; the v_rcp (~60 cyc) inside the cycle is.
// Fix: predictive reciprocal seed. p = 0.99*theta + 0.09 is computable one
// full step early (s-independent); theta_next differs from p by
// 0.01*s - 0.08 (|.| <= 0.08). On the critical path: first-order-correct
// the seed with delta (2 fma gated only by s), then 3 Newton-Raphson
// against the EXACT theta: 5.6e-3 -> 3e-5 -> 1e-9 -> 1e-17 rel error, so
// rr is the <=0.5-ulp reciprocal and the Markstein tail yields the same
// unique correctly-rounded quotient bits as R5-R10 (absmax 0.0). The
// rcp's 60-cyc latency is fully off the inter-step cycle.
// v/theta update expressions are VERBATIM (bit-exact) — DO NOT touch.
// ---------------------------------------------------------------------------
#define SPF 32

__device__ __forceinline__
void scan_steps(const float* __restrict__ buf, float* __restrict__ sp,
                int tb, float& v, float& theta, float& rp, float& s_prev) {
    const float DECAY_F = 0.9048374180359595f;  // exp(-1/10)
    const float ALPHA_F = 0.01f;
#pragma unroll
    for (int j = 0; j < SPF; ++j) {
        float cur = buf[j];
        v = v * DECAY_F + cur;
        float cl = 32.0f * theta;                  // L * theta * 2
        v = __builtin_amdgcn_fmed3f(v, -cl, cl);   // == fminf(fmaxf(v,-cl),cl)

        // ---- correctly-rounded v/theta, rcp off the critical cycle ----
        float dlt = fmaf(0.01f, s_prev, -0.08f);   // theta - p (approx)
        float tcr = fmaf(-rp, dlt, 1.0f);
        float rr  = rp * tcr;                      // seed, rel err <= 5.6e-3
        float e;
        e = fmaf(-theta, rr, 1.0f);  rr = fmaf(rr, e, rr);   // -> 3e-5
        e = fmaf(-theta, rr, 1.0f);  rr = fmaf(rr, e, rr);   // -> 1e-9
        e = fmaf(-theta, rr, 1.0f);  rr = fmaf(rr, e, rr);   // -> 1e-17
        float q0 = v * rr;
        float er = fmaf(-theta, q0, v);            // exact residual
        float q  = fmaf(er, rr, q0);               // correctly-rounded quotient
        // ---------------------------------------------------------------

        float s = floorf(q);
        s = __builtin_amdgcn_fmed3f(s, 0.0f, 16.0f); // == fminf(fmaxf(s,0),16)
        v = v - s * theta;
        theta = theta + ALPHA_F * s - ALPHA_F * (theta - 1.0f);

        // next step's reciprocal seed: issued now, latency fully hidden
        rp = __builtin_amdgcn_rcpf(fmaf(0.99f, theta, 0.09f));
        s_prev = s;

        sp[(size_t)(tb + j) * H_] = s;
    }
}

__global__ __launch_bounds__(64)
void gif_scan(const float* __restrict__ Hbuf, float* __restrict__ spikes,
              float* __restrict__ vout, float* __restrict__ thout) {
    const int gid = blockIdx.x * 64 + threadIdx.x;    // 0..8191
    const int b = gid >> 9;
    const int h = gid & 511;

    const float* ip = Hbuf   + (size_t)b * T_ * H_ + h;
    float*       sp = spikes + (size_t)b * T_ * H_ + h;

    float bufA[SPF], bufB[SPF];
#pragma unroll
    for (int j = 0; j < SPF; ++j) bufA[j] = ip[(size_t)j * H_];

    float v = 0.0f, theta = 1.0f;
    // seed init consistent with the delta convention: p = 0.99*1 + 0.09,
    // s_prev = 0  ->  theta0 - p = -0.08 = 0.01*0 - 0.08.  3 N-R converge.
    float rp = __builtin_amdgcn_rcpf(1.08f);
    float s_prev = 0.0f;

    for (int t0 = 0; t0 < T_; t0 += 2 * SPF) {        // 32 iters, no tail
#pragma unroll
        for (int j = 0; j < SPF; ++j) bufB[j] = ip[(size_t)(t0 + SPF + j) * H_];
        asm volatile("" ::: "memory");
        scan_steps(bufA, sp, t0, v, theta, rp, s_prev);

        if (t0 + 2 * SPF < T_) {
#pragma unroll
            for (int j = 0; j < SPF; ++j)
                bufA[j] = ip[(size_t)(t0 + 2 * SPF + j) * H_];
        }
        asm volatile("" ::: "memory");
        scan_steps(bufB, sp, t0 + SPF, v, theta, rp, s_prev);
    }
    vout[gid]  = v;
    thout[gid] = theta;
}

// ---------------------------------------------------------------------------
extern "C" void kernel_launch(void* const* d_in, const int* in_sizes, int n_in,
                              void* d_out, int out_size, void* d_ws, size_t ws_size,
                              hipStream_t stream) {
    const float* x    = (const float*)d_in[0];   // [16, 2048, 512]
    const float* W    = (const float*)d_in[1];   // [512, 512]
    const float* bias = (const float*)d_in[2];   // [512]

    float* out    = (float*)d_out;
    float* spikes = out;
    float* v_f    = out + (size_t)M_ * H_;
    float* th_f   = v_f + (size_t)B_ * H_;

    float* hbuf   = (float*)d_ws;                // 64 MiB scratch for h

    dim3 grid(M_ / BM, H_ / BN);                 // 256 x 4
    gemm_xwT<<<grid, 256, 0, stream>>>(x, W, bias, hbuf);
    gif_scan<<<(B_ * H_) / 64, 64, 0, stream>>>(hbuf, spikes, v_f, th_f);
}